// Round 7
// baseline (252.502 us; speedup 1.0000x reference)
//
#include <hip/hip_runtime.h>
#include <float.h>
#include <math.h>

#define NV 50257
#define D 128
#define B 2048
#define C 10

#define NVPAD 50272                 // 3142 * 16
#define NTILES (NVPAD / 16)         // 3142 col-tiles of 16
#define NSTREAM 128                 // vocab streams; grid 1024 = 4 blocks/CU exactly
#define NG4 (NVPAD * D / 4)         // float4 count of padded W_gen
#define LOG2E 1.44269504088896f

typedef __attribute__((ext_vector_type(8))) short short8;
typedef __attribute__((ext_vector_type(4))) float float4v;

__device__ __forceinline__ float softplus_f(float x) {
    return fmaxf(x, 0.f) + log1pf(expf(-fabsf(x)));
}

__device__ __forceinline__ short f2bf(float f) {
    unsigned u = __float_as_uint(f);
    unsigned r = (u + 0x7FFFu + ((u >> 16) & 1u)) >> 16;   // RNE
    return (short)r;
}

// ---------------- Kernel W: bf16 converts + bg2 table + out zeroing ----------------
__global__ __launch_bounds__(256) void k_convert(
    const float* __restrict__ wg, const float* __restrict__ waff,
    const float* __restrict__ wmu, const float* __restrict__ wsig,
    const float* __restrict__ b_gen,
    short* __restrict__ wg_o, short* __restrict__ waff_o,
    short* __restrict__ wmu_o, short* __restrict__ wsig_o,
    float* __restrict__ bg2, float* __restrict__ out)
{
    const int i4 = blockIdx.x * 256 + threadIdx.x;      // float4 index
    if (i4 == 0) out[0] = 0.f;
    if (i4 < NG4) {
        const int e0 = i4 * 4;
        short4 o;
        if (e0 < NV * D) {
            const float4 g = ((const float4*)wg)[i4];
            o.x = f2bf(g.x); o.y = f2bf(g.y); o.z = f2bf(g.z); o.w = f2bf(g.w);
        } else {
            o.x = o.y = o.z = o.w = 0;
        }
        ((short4*)wg_o)[i4] = o;
        return;
    }
    const int j = i4 - NG4;
    if (j < 16384) {
        const float4* src; short4* dst; int jj;
        if (j < 8192)       { src = (const float4*)waff; dst = (short4*)waff_o; jj = j; }
        else if (j < 12288) { src = (const float4*)wmu;  dst = (short4*)wmu_o;  jj = j - 8192; }
        else                { src = (const float4*)wsig; dst = (short4*)wsig_o; jj = j - 12288; }
        const float4 g = src[jj];
        short4 o;
        o.x = f2bf(g.x); o.y = f2bf(g.y); o.z = f2bf(g.z); o.w = f2bf(g.w);
        dst[jj] = o;
    } else {
        const int jj = j - 16384;                       // bg2 float4 index
        if (jj < NVPAD / 4) {
            const int e0 = jj * 4;
            float4 o;
            o.x = (e0 + 0 < NV) ? b_gen[e0 + 0] * LOG2E : -INFINITY;
            o.y = (e0 + 1 < NV) ? b_gen[e0 + 1] * LOG2E : -INFINITY;
            o.z = (e0 + 2 < NV) ? b_gen[e0 + 2] * LOG2E : -INFINITY;
            o.w = (e0 + 3 < NV) ? b_gen[e0 + 3] * LOG2E : -INFINITY;
            ((float4*)bg2)[jj] = o;
        }
    }
}

// ---------------- Kernel A: merged inference net ----------------
// grid 128 x 512 thr (8 waves). Phase 1: wave w computes U (redundant) + ctx c=w
// (+ c=8+w for w<2), partial H -> LDS slab. Phase 2: wave w sums 8 slabs into
// A-frags, GEMM2 for nt-tile w, fused epilogue (softplus/z/zb/KL).
__global__ __launch_bounds__(512) void k_infer(
    const int* __restrict__ x_batch, const int* __restrict__ ctxw,
    const float* __restrict__ eps, const float* __restrict__ inf_emb,
    const short* __restrict__ waff_bf, const float* __restrict__ b_aff,
    const short* __restrict__ wmu_bf, const float* __restrict__ b_mu,
    const short* __restrict__ wsig_bf, const float* __restrict__ b_sig,
    const float* __restrict__ gen_sig_emb,
    float* __restrict__ z_out, short* __restrict__ zb_out,
    float* __restrict__ kl_out)
{
    const int b0 = blockIdx.x * 16;
    const int t = threadIdx.x;
    const int wv = t >> 6;           // 0..7
    const int lane = t & 63;
    const int col16 = lane & 15;
    const int quad = lane >> 4;

    __shared__ float hsp[8][16][132];
    __shared__ float kl_s[8][16];

    const int brow = b0 + col16;
    const int cidx = x_batch[brow];

    // center A-frags
    short8 ce[4];
    #pragma unroll
    for (int ks = 0; ks < 4; ++ks) {
        const float* p = inf_emb + (size_t)cidx * D + ks * 32 + quad * 8;
        const float4 g0 = *(const float4*)p;
        const float4 g1 = *(const float4*)(p + 4);
        short8 v;
        v[0] = f2bf(g0.x); v[1] = f2bf(g0.y); v[2] = f2bf(g0.z); v[3] = f2bf(g0.w);
        v[4] = f2bf(g1.x); v[5] = f2bf(g1.y); v[6] = f2bf(g1.z); v[7] = f2bf(g1.w);
        ce[ks] = v;
    }

    // U = center @ W1^T (redundant per wave)
    float4v U[8];
    #pragma unroll
    for (int dt = 0; dt < 8; ++dt) {
        float4v acc = {0.f, 0.f, 0.f, 0.f};
        #pragma unroll
        for (int ks = 0; ks < 4; ++ks) {
            const short8 bw = *(const short8*)(waff_bf + (dt * 16 + col16) * 256 + ks * 32 + quad * 8);
            acc = __builtin_amdgcn_mfma_f32_16x16x32_bf16(ce[ks], bw, acc, 0, 0, 0);
        }
        U[dt] = acc;
    }
    float ba[8];
    #pragma unroll
    for (int dt = 0; dt < 8; ++dt) ba[dt] = b_aff[dt * 16 + col16];

    float4v H[8];
    #pragma unroll
    for (int dt = 0; dt < 8; ++dt) H[dt] = (float4v){0.f, 0.f, 0.f, 0.f};

    // wave wv: ctx wv, and ctx 8+wv when wv<2
    const int nctx = (wv < 2) ? 2 : 1;
    for (int cc = 0; cc < nctx; ++cc) {
        const int c = wv + cc * 8;
        const int widx = ctxw[brow * C + c];
        short8 cx[4];
        #pragma unroll
        for (int ks = 0; ks < 4; ++ks) {
            const float* p = inf_emb + (size_t)widx * D + ks * 32 + quad * 8;
            const float4 g0 = *(const float4*)p;
            const float4 g1 = *(const float4*)(p + 4);
            short8 v;
            v[0] = f2bf(g0.x); v[1] = f2bf(g0.y); v[2] = f2bf(g0.z); v[3] = f2bf(g0.w);
            v[4] = f2bf(g1.x); v[5] = f2bf(g1.y); v[6] = f2bf(g1.z); v[7] = f2bf(g1.w);
            cx[ks] = v;
        }
        #pragma unroll
        for (int dt = 0; dt < 8; ++dt) {
            float4v a = {0.f, 0.f, 0.f, 0.f};
            #pragma unroll
            for (int ks = 0; ks < 4; ++ks) {
                const short8 bw = *(const short8*)(waff_bf + (dt * 16 + col16) * 256 + 128 + ks * 32 + quad * 8);
                a = __builtin_amdgcn_mfma_f32_16x16x32_bf16(cx[ks], bw, a, 0, 0, 0);
            }
            #pragma unroll
            for (int r = 0; r < 4; ++r)
                H[dt][r] += fmaxf(U[dt][r] + a[r] + ba[dt], 0.f);
        }
    }

    // partial H -> LDS slab (C-layout scatter)
    #pragma unroll
    for (int dt = 0; dt < 8; ++dt)
        #pragma unroll
        for (int r = 0; r < 4; ++r)
            hsp[wv][quad * 4 + r][dt * 16 + col16] = H[dt][r];
    __syncthreads();

    // ha = sum of 8 slabs, A-layout
    short8 ha[4];
    #pragma unroll
    for (int ks = 0; ks < 4; ++ks) {
        const int off = ks * 32 + quad * 8;
        float4 s0 = {0.f, 0.f, 0.f, 0.f}, s1 = {0.f, 0.f, 0.f, 0.f};
        #pragma unroll
        for (int w = 0; w < 8; ++w) {
            const float4 a0 = *(const float4*)&hsp[w][col16][off];
            const float4 a1 = *(const float4*)&hsp[w][col16][off + 4];
            s0.x += a0.x; s0.y += a0.y; s0.z += a0.z; s0.w += a0.w;
            s1.x += a1.x; s1.y += a1.y; s1.z += a1.z; s1.w += a1.w;
        }
        short8 v;
        v[0] = f2bf(s0.x); v[1] = f2bf(s0.y); v[2] = f2bf(s0.z); v[3] = f2bf(s0.w);
        v[4] = f2bf(s1.x); v[5] = f2bf(s1.y); v[6] = f2bf(s1.z); v[7] = f2bf(s1.w);
        ha[ks] = v;
    }

    // GEMM2 + epilogue: wave wv handles nt = wv
    int xb2[4];
    #pragma unroll
    for (int r = 0; r < 4; ++r) xb2[r] = x_batch[b0 + quad * 4 + r];

    float klp[4] = {0.f, 0.f, 0.f, 0.f};
    {
        const int nt = wv;
        float4v mu4 = {0.f, 0.f, 0.f, 0.f};
        float4v sg4 = {0.f, 0.f, 0.f, 0.f};
        #pragma unroll
        for (int ks = 0; ks < 4; ++ks) {
            const short8 bm = *(const short8*)(wmu_bf + (nt * 16 + col16) * 128 + ks * 32 + quad * 8);
            const short8 bs = *(const short8*)(wsig_bf + (nt * 16 + col16) * 128 + ks * 32 + quad * 8);
            mu4 = __builtin_amdgcn_mfma_f32_16x16x32_bf16(ha[ks], bm, mu4, 0, 0, 0);
            sg4 = __builtin_amdgcn_mfma_f32_16x16x32_bf16(ha[ks], bs, sg4, 0, 0, 0);
        }
        const int d = nt * 16 + col16;
        const float bmu = b_mu[d];
        const float bsg = b_sig[d];
        #pragma unroll
        for (int r = 0; r < 4; ++r) {
            const int b = b0 + quad * 4 + r;
            const float mu = mu4[r] + bmu;
            const float sg = sg4[r] + bsg;
            const float isig = softplus_f(sg);
            const float e = eps[b * D + d];
            const float zz = fmaf(e, isig, mu);
            z_out[b * D + d] = zz;
            zb_out[b * D + d] = f2bf(zz * LOG2E);    // pre-scaled: LSE works in log2
            const float gs = softplus_f(gen_sig_emb[(size_t)xb2[r] * D + d]);
            const float diff = mu - gs;
            klp[r] += logf(gs / isig) + (isig * isig + diff * diff) / (2.f * gs * gs) - 0.5f;
        }
    }
    #pragma unroll
    for (int off = 1; off < 16; off <<= 1)
        #pragma unroll
        for (int r = 0; r < 4; ++r)
            klp[r] += __shfl_xor(klp[r], off, 64);
    if (col16 == 0) {
        #pragma unroll
        for (int r = 0; r < 4; ++r)
            kl_s[wv][quad * 4 + r] = klp[r];
    }
    __syncthreads();
    if (t < 16) {
        float s = 0.f;
        #pragma unroll
        for (int w = 0; w < 8; ++w) s += kl_s[w][t];
        kl_out[b0 + t] = s;
    }
}

// ---------------- Kernel B: MFMA sum-exp, 2-buffer pipeline, bias in acc-init ---------
// grid 1024 = 8 row-blocks x 128 streams (bid = x*128 + s); XCD = bid%8 = s%8.
// __launch_bounds__(256,4): <=128 VGPR -> 16 waves/CU resident (4 blocks/CU exactly).
#define LOADT(bf, g, T) { \
    const int v_ = (T) < NTILES; \
    const int tt_ = v_ ? (T) : 0; \
    const short* wp_ = wb + (size_t)(tt_ * 16 + col16) * D + quad * 8; \
    bf[0] = *(const short8*)(wp_); \
    bf[1] = *(const short8*)(wp_ + 32); \
    bf[2] = *(const short8*)(wp_ + 64); \
    bf[3] = *(const short8*)(wp_ + 96); \
    g = v_ ? bg2t[tt_ * 16 + col16] : -INFINITY; }

#define COMPT(bf, g) { \
    _Pragma("unroll") \
    for (int rt = 0; rt < 4; ++rt) { \
        float4v c = {g, g, g, g}; \
        _Pragma("unroll") \
        for (int ks = 0; ks < 4; ++ks) \
            c = __builtin_amdgcn_mfma_f32_16x16x32_bf16(afrag[rt][ks], bf[ks], c, 0, 0, 0); \
        _Pragma("unroll") \
        for (int r = 0; r < 4; ++r) \
            sums[rt][r] += __builtin_amdgcn_exp2f(c[r]); \
    } }

__global__ __launch_bounds__(256, 4) void k_lse_mfma(
    const short* __restrict__ zb, const short* __restrict__ wb,
    const float* __restrict__ bg2t, float* __restrict__ part_s)
{
    const int bid = blockIdx.x;
    const int s = bid & 127;                        // stream; XCD = s%8
    const int x = bid >> 7;                         // row block (256 rows)
    const int t = threadIdx.x;
    const int wv = t >> 6;
    const int lane = t & 63;
    const int col16 = lane & 15;
    const int quad = lane >> 4;
    const int rowbase = x * 256 + wv * 64;

    short8 afrag[4][4];
    #pragma unroll
    for (int rt = 0; rt < 4; ++rt)
        #pragma unroll
        for (int ks = 0; ks < 4; ++ks)
            afrag[rt][ks] = *(const short8*)(zb + (rowbase + rt * 16 + col16) * D
                                                + ks * 32 + quad * 8);

    float sums[4][4];
    #pragma unroll
    for (int rt = 0; rt < 4; ++rt)
        #pragma unroll
        for (int r = 0; r < 4; ++r) sums[rt][r] = 0.f;

    // 25 tiles/stream (ceil(3142/128)); clamped tails contribute exp2(-inf)=0.
    short8 bA[4], bB[4];
    float gA, gB;
    LOADT(bA, gA, s);
    #pragma unroll 1
    for (int p = 0; p < 12; ++p) {
        LOADT(bB, gB, s + (2 * p + 1) * 128);
        COMPT(bA, gA);
        LOADT(bA, gA, s + (2 * p + 2) * 128);
        COMPT(bB, gB);
    }
    COMPT(bA, gA);                                  // tile 24

    #pragma unroll
    for (int off = 1; off < 16; off <<= 1)
        #pragma unroll
        for (int rt = 0; rt < 4; ++rt)
            #pragma unroll
            for (int r = 0; r < 4; ++r)
                sums[rt][r] += __shfl_xor(sums[rt][r], off, 64);

    if (col16 == 0) {
        #pragma unroll
        for (int rt = 0; rt < 4; ++rt)
            #pragma unroll
            for (int r = 0; r < 4; ++r) {
                const int row = rowbase + rt * 16 + quad * 4 + r;
                part_s[row * NSTREAM + s] = sums[rt][r];
            }
    }
}

// ---------------- Kernel C: finalize, 8 rows/block, one atomic per block ----------------
__global__ __launch_bounds__(256) void k_final(
    const float* __restrict__ z, const short* __restrict__ wb,
    const float* __restrict__ b_gen, const int* __restrict__ ctxw,
    const float* __restrict__ part_s, const float* __restrict__ kl,
    float* __restrict__ out)
{
    const int t = threadIdx.x;
    const int wv = t >> 6;
    const int lane = t & 63;
    __shared__ float red[4];

    float wsum = 0.f;
    #pragma unroll
    for (int rr = 0; rr < 2; ++rr) {
        const int b = blockIdx.x * 8 + wv * 2 + rr;

        int idxs[C];
        #pragma unroll
        for (int c = 0; c < C; ++c) idxs[c] = ctxw[b * C + c];
        unsigned uw[C];
        #pragma unroll
        for (int c = 0; c < C; ++c)
            uw[c] = ((const unsigned*)(wb + (size_t)idxs[c] * D))[lane];
        float sum_bg = 0.f;
        #pragma unroll
        for (int c = 0; c < C; ++c) sum_bg += b_gen[idxs[c]];

        float sv = part_s[b * NSTREAM + lane] + part_s[b * NSTREAM + 64 + lane];
        const float z0 = z[b * D + lane * 2];
        const float z1 = z[b * D + lane * 2 + 1];

        float acc = 0.f;
        #pragma unroll
        for (int c = 0; c < C; ++c) {
            const float w0 = __uint_as_float(uw[c] << 16);
            const float w1 = __uint_as_float(uw[c] & 0xFFFF0000u);
            acc = fmaf(z0, w0, acc);
            acc = fmaf(z1, w1, acc);
        }
        #pragma unroll
        for (int off = 32; off > 0; off >>= 1) {
            sv  += __shfl_xor(sv, off, 64);
            acc += __shfl_xor(acc, off, 64);
        }
        if (lane == 0) {
            const float lse = logf(sv);
            const float recon = acc + sum_bg - C * lse;
            wsum += kl[b] - recon;
        }
    }
    if (lane == 0) red[wv] = wsum;
    __syncthreads();
    if (t == 0) atomicAdd(out, (red[0] + red[1] + red[2] + red[3]) * (1.f / B));
}

extern "C" void kernel_launch(void* const* d_in, const int* in_sizes, int n_in,
                              void* d_out, int out_size, void* d_ws, size_t ws_size,
                              hipStream_t stream) {
    const int* x_batch = (const int*)d_in[0];
    const int* ctxw    = (const int*)d_in[1];
    const float* eps   = (const float*)d_in[2];
    const float* inf_emb = (const float*)d_in[3];
    const float* W_aff = (const float*)d_in[4];
    const float* b_aff = (const float*)d_in[5];
    const float* W_mu  = (const float*)d_in[6];
    const float* b_mu  = (const float*)d_in[7];
    const float* W_sig = (const float*)d_in[8];
    const float* b_sig = (const float*)d_in[9];
    const float* gen_sig = (const float*)d_in[10];
    const float* W_gen = (const float*)d_in[11];
    const float* b_gen = (const float*)d_in[12];
    float* out = (float*)d_out;

    char* ws = (char*)d_ws;
    float* z      = (float*)ws;   ws += (size_t)B * D * 4;
    float* part_s = (float*)ws;   ws += (size_t)B * NSTREAM * 4;
    float* kl     = (float*)ws;   ws += (size_t)B * 4;
    float* bg2    = (float*)ws;   ws += (size_t)NVPAD * 4;
    short* z_bf   = (short*)ws;   ws += (size_t)B * D * 2;
    short* w_bf   = (short*)ws;   ws += (size_t)NVPAD * D * 2;
    short* waff_bf = (short*)ws;  ws += (size_t)128 * 256 * 2;
    short* wmu_bf  = (short*)ws;  ws += (size_t)128 * 128 * 2;
    short* wsig_bf = (short*)ws;  ws += (size_t)128 * 128 * 2;

    const int conv_items = NG4 + 16384 + NVPAD / 4;
    hipLaunchKernelGGL(k_convert, dim3((conv_items + 255) / 256), dim3(256), 0, stream,
                       W_gen, W_aff, W_mu, W_sig, b_gen,
                       w_bf, waff_bf, wmu_bf, wsig_bf, bg2, out);
    hipLaunchKernelGGL(k_infer, dim3(B / 16), dim3(512), 0, stream,
                       x_batch, ctxw, eps, inf_emb, waff_bf, b_aff, wmu_bf, b_mu,
                       wsig_bf, b_sig, gen_sig, z, z_bf, kl);
    hipLaunchKernelGGL(k_lse_mfma, dim3(8 * NSTREAM), dim3(256), 0, stream,
                       z_bf, w_bf, bg2, part_s);
    hipLaunchKernelGGL(k_final, dim3(B / 8), dim3(256), 0, stream,
                       z, w_bf, b_gen, ctxw, part_s, kl, out);
}

// Round 8
// 190.366 us; speedup vs baseline: 1.3264x; 1.3264x over previous
//
#include <hip/hip_runtime.h>
#include <float.h>
#include <math.h>

#define NV 50257
#define D 128
#define B 2048
#define C 10

#define NVPAD 50272                 // 3142 * 16
#define NTILES (NVPAD / 16)         // 3142 col-tiles of 16
#define NSTREAM 128                 // vocab streams
#define NG4 (NVPAD * D / 4)         // float4 count of padded W_gen
#define LOG2E 1.44269504088896f
#define SC1 0x7F7F7F7F              // e8m0 scale = 1.0 in every byte

typedef __attribute__((ext_vector_type(8))) short short8;
typedef __attribute__((ext_vector_type(8))) int int8v;
typedef __attribute__((ext_vector_type(4))) float float4v;

__device__ __forceinline__ float softplus_f(float x) {
    return fmaxf(x, 0.f) + log1pf(expf(-fabsf(x)));
}

__device__ __forceinline__ short f2bf(float f) {
    unsigned u = __float_as_uint(f);
    unsigned r = (u + 0x7FFFu + ((u >> 16) & 1u)) >> 16;   // RNE
    return (short)r;
}

// ---------------- Kernel W: fp8 W_gen + bf16 small weights + bg2 + out zero ----------------
__global__ __launch_bounds__(256) void k_convert(
    const float* __restrict__ wg, const float* __restrict__ waff,
    const float* __restrict__ wmu, const float* __restrict__ wsig,
    const float* __restrict__ b_gen,
    unsigned char* __restrict__ w8_o, short* __restrict__ waff_o,
    short* __restrict__ wmu_o, short* __restrict__ wsig_o,
    float* __restrict__ bg2, float* __restrict__ out)
{
    const int i4 = blockIdx.x * 256 + threadIdx.x;      // float4 index
    if (i4 == 0) out[0] = 0.f;
    if (i4 < NG4) {
        const int e0 = i4 * 4;
        int pk = 0;
        if (e0 < NV * D) {
            const float4 g = ((const float4*)wg)[i4];
            pk = __builtin_amdgcn_cvt_pk_fp8_f32(g.x, g.y, 0, false);
            pk = __builtin_amdgcn_cvt_pk_fp8_f32(g.z, g.w, pk, true);
        }
        ((int*)w8_o)[i4] = pk;                           // 4 fp8 bytes, k-contiguous
        return;
    }
    const int j = i4 - NG4;
    if (j < 16384) {
        const float4* src; short4* dst; int jj;
        if (j < 8192)       { src = (const float4*)waff; dst = (short4*)waff_o; jj = j; }
        else if (j < 12288) { src = (const float4*)wmu;  dst = (short4*)wmu_o;  jj = j - 8192; }
        else                { src = (const float4*)wsig; dst = (short4*)wsig_o; jj = j - 12288; }
        const float4 g = src[jj];
        short4 o;
        o.x = f2bf(g.x); o.y = f2bf(g.y); o.z = f2bf(g.z); o.w = f2bf(g.w);
        dst[jj] = o;
    } else {
        const int jj = j - 16384;                       // bg2 float4 index
        if (jj < NVPAD / 4) {
            const int e0 = jj * 4;
            float4 o;
            o.x = (e0 + 0 < NV) ? b_gen[e0 + 0] * LOG2E : -INFINITY;
            o.y = (e0 + 1 < NV) ? b_gen[e0 + 1] * LOG2E : -INFINITY;
            o.z = (e0 + 2 < NV) ? b_gen[e0 + 2] * LOG2E : -INFINITY;
            o.w = (e0 + 3 < NV) ? b_gen[e0 + 3] * LOG2E : -INFINITY;
            ((float4*)bg2)[jj] = o;
        }
    }
}

// ---------------- Kernel A: merged inference net (8 waves, ctx-parallel) ----------------
__global__ __launch_bounds__(512) void k_infer(
    const int* __restrict__ x_batch, const int* __restrict__ ctxw,
    const float* __restrict__ eps, const float* __restrict__ inf_emb,
    const short* __restrict__ waff_bf, const float* __restrict__ b_aff,
    const short* __restrict__ wmu_bf, const float* __restrict__ b_mu,
    const short* __restrict__ wsig_bf, const float* __restrict__ b_sig,
    const float* __restrict__ gen_sig_emb,
    float* __restrict__ z_out, unsigned char* __restrict__ z8_out,
    float* __restrict__ kl_out)
{
    const int b0 = blockIdx.x * 16;
    const int t = threadIdx.x;
    const int wv = t >> 6;           // 0..7
    const int lane = t & 63;
    const int col16 = lane & 15;
    const int quad = lane >> 4;

    __shared__ float hsp[8][16][132];
    __shared__ float kl_s[8][16];

    const int brow = b0 + col16;
    const int cidx = x_batch[brow];

    short8 ce[4];
    #pragma unroll
    for (int ks = 0; ks < 4; ++ks) {
        const float* p = inf_emb + (size_t)cidx * D + ks * 32 + quad * 8;
        const float4 g0 = *(const float4*)p;
        const float4 g1 = *(const float4*)(p + 4);
        short8 v;
        v[0] = f2bf(g0.x); v[1] = f2bf(g0.y); v[2] = f2bf(g0.z); v[3] = f2bf(g0.w);
        v[4] = f2bf(g1.x); v[5] = f2bf(g1.y); v[6] = f2bf(g1.z); v[7] = f2bf(g1.w);
        ce[ks] = v;
    }

    float4v U[8];
    #pragma unroll
    for (int dt = 0; dt < 8; ++dt) {
        float4v acc = {0.f, 0.f, 0.f, 0.f};
        #pragma unroll
        for (int ks = 0; ks < 4; ++ks) {
            const short8 bw = *(const short8*)(waff_bf + (dt * 16 + col16) * 256 + ks * 32 + quad * 8);
            acc = __builtin_amdgcn_mfma_f32_16x16x32_bf16(ce[ks], bw, acc, 0, 0, 0);
        }
        U[dt] = acc;
    }
    float ba[8];
    #pragma unroll
    for (int dt = 0; dt < 8; ++dt) ba[dt] = b_aff[dt * 16 + col16];

    float4v H[8];
    #pragma unroll
    for (int dt = 0; dt < 8; ++dt) H[dt] = (float4v){0.f, 0.f, 0.f, 0.f};

    const int nctx = (wv < 2) ? 2 : 1;
    for (int cc = 0; cc < nctx; ++cc) {
        const int c = wv + cc * 8;
        const int widx = ctxw[brow * C + c];
        short8 cx[4];
        #pragma unroll
        for (int ks = 0; ks < 4; ++ks) {
            const float* p = inf_emb + (size_t)widx * D + ks * 32 + quad * 8;
            const float4 g0 = *(const float4*)p;
            const float4 g1 = *(const float4*)(p + 4);
            short8 v;
            v[0] = f2bf(g0.x); v[1] = f2bf(g0.y); v[2] = f2bf(g0.z); v[3] = f2bf(g0.w);
            v[4] = f2bf(g1.x); v[5] = f2bf(g1.y); v[6] = f2bf(g1.z); v[7] = f2bf(g1.w);
            cx[ks] = v;
        }
        #pragma unroll
        for (int dt = 0; dt < 8; ++dt) {
            float4v a = {0.f, 0.f, 0.f, 0.f};
            #pragma unroll
            for (int ks = 0; ks < 4; ++ks) {
                const short8 bw = *(const short8*)(waff_bf + (dt * 16 + col16) * 256 + 128 + ks * 32 + quad * 8);
                a = __builtin_amdgcn_mfma_f32_16x16x32_bf16(cx[ks], bw, a, 0, 0, 0);
            }
            #pragma unroll
            for (int r = 0; r < 4; ++r)
                H[dt][r] += fmaxf(U[dt][r] + a[r] + ba[dt], 0.f);
        }
    }

    #pragma unroll
    for (int dt = 0; dt < 8; ++dt)
        #pragma unroll
        for (int r = 0; r < 4; ++r)
            hsp[wv][quad * 4 + r][dt * 16 + col16] = H[dt][r];
    __syncthreads();

    short8 ha[4];
    #pragma unroll
    for (int ks = 0; ks < 4; ++ks) {
        const int off = ks * 32 + quad * 8;
        float4 s0 = {0.f, 0.f, 0.f, 0.f}, s1 = {0.f, 0.f, 0.f, 0.f};
        #pragma unroll
        for (int w = 0; w < 8; ++w) {
            const float4 a0 = *(const float4*)&hsp[w][col16][off];
            const float4 a1 = *(const float4*)&hsp[w][col16][off + 4];
            s0.x += a0.x; s0.y += a0.y; s0.z += a0.z; s0.w += a0.w;
            s1.x += a1.x; s1.y += a1.y; s1.z += a1.z; s1.w += a1.w;
        }
        short8 v;
        v[0] = f2bf(s0.x); v[1] = f2bf(s0.y); v[2] = f2bf(s0.z); v[3] = f2bf(s0.w);
        v[4] = f2bf(s1.x); v[5] = f2bf(s1.y); v[6] = f2bf(s1.z); v[7] = f2bf(s1.w);
        ha[ks] = v;
    }

    int xb2[4];
    #pragma unroll
    for (int r = 0; r < 4; ++r) xb2[r] = x_batch[b0 + quad * 4 + r];

    float klp[4] = {0.f, 0.f, 0.f, 0.f};
    {
        const int nt = wv;
        float4v mu4 = {0.f, 0.f, 0.f, 0.f};
        float4v sg4 = {0.f, 0.f, 0.f, 0.f};
        #pragma unroll
        for (int ks = 0; ks < 4; ++ks) {
            const short8 bm = *(const short8*)(wmu_bf + (nt * 16 + col16) * 128 + ks * 32 + quad * 8);
            const short8 bs = *(const short8*)(wsig_bf + (nt * 16 + col16) * 128 + ks * 32 + quad * 8);
            mu4 = __builtin_amdgcn_mfma_f32_16x16x32_bf16(ha[ks], bm, mu4, 0, 0, 0);
            sg4 = __builtin_amdgcn_mfma_f32_16x16x32_bf16(ha[ks], bs, sg4, 0, 0, 0);
        }
        const int d = nt * 16 + col16;
        const float bmu = b_mu[d];
        const float bsg = b_sig[d];
        #pragma unroll
        for (int r = 0; r < 4; ++r) {
            const int b = b0 + quad * 4 + r;
            const float mu = mu4[r] + bmu;
            const float sg = sg4[r] + bsg;
            const float isig = softplus_f(sg);
            const float e = eps[b * D + d];
            const float zz = fmaf(e, isig, mu);
            z_out[b * D + d] = zz;
            // fp8 of z * log2e (HW cvt, RNE); LSE kernel works in log2 domain
            const int pk = __builtin_amdgcn_cvt_pk_fp8_f32(zz * LOG2E, 0.f, 0, false);
            z8_out[b * D + d] = (unsigned char)(pk & 0xFF);
            const float gs = softplus_f(gen_sig_emb[(size_t)xb2[r] * D + d]);
            const float diff = mu - gs;
            klp[r] += logf(gs / isig) + (isig * isig + diff * diff) / (2.f * gs * gs) - 0.5f;
        }
    }
    #pragma unroll
    for (int off = 1; off < 16; off <<= 1)
        #pragma unroll
        for (int r = 0; r < 4; ++r)
            klp[r] += __shfl_xor(klp[r], off, 64);
    if (col16 == 0) {
        #pragma unroll
        for (int r = 0; r < 4; ++r)
            kl_s[wv][quad * 4 + r] = klp[r];
    }
    __syncthreads();
    if (t < 16) {
        float s = 0.f;
        #pragma unroll
        for (int w = 0; w < 8; ++w) s += kl_s[w][t];
        kl_out[b0 + t] = s;
    }
}

// ---------------- Kernel B: MX-fp8 K=128 MFMA sum-exp, 4-tile register pipeline --------
// grid 1024 = 8 row-blocks x 128 streams; XCD = s%8 (stream's 8 row-blocks share L2).
// One mfma_scale_f32_16x16x128_f8f6f4 per row-tile covers the whole K; bias in acc-init.
#define LOADT8(bf, g, T) { \
    const int v_ = (T) < NTILES; \
    const int tt_ = v_ ? (T) : 0; \
    bf = *(const int8v*)(w8 + (size_t)(tt_ * 16 + col16) * D + quad * 32); \
    g = v_ ? bg2t[tt_ * 16 + col16] : -INFINITY; }

#define COMP8(bf, g) { \
    _Pragma("unroll") \
    for (int rt = 0; rt < 4; ++rt) { \
        float4v c = {g, g, g, g}; \
        c = __builtin_amdgcn_mfma_scale_f32_16x16x128_f8f6f4( \
                afrag[rt], bf, c, 0, 0, 0, SC1, 0, SC1); \
        _Pragma("unroll") \
        for (int r = 0; r < 4; ++r) \
            sums[rt][r] += __builtin_amdgcn_exp2f(c[r]); \
    } }

__global__ __launch_bounds__(256) void k_lse_mfma(
    const unsigned char* __restrict__ z8, const unsigned char* __restrict__ w8,
    const float* __restrict__ bg2t, float* __restrict__ part_s)
{
    const int bid = blockIdx.x;
    const int s = bid & 127;                        // stream; XCD = s%8
    const int x = bid >> 7;                         // row block (256 rows)
    const int t = threadIdx.x;
    const int wv = t >> 6;
    const int lane = t & 63;
    const int col16 = lane & 15;
    const int quad = lane >> 4;
    const int rowbase = x * 256 + wv * 64;

    // A-frags: lane (m=col16, k=quad*32..+32), 32 B = 8 dwords, 32-B aligned
    int8v afrag[4];
    #pragma unroll
    for (int rt = 0; rt < 4; ++rt)
        afrag[rt] = *(const int8v*)(z8 + (size_t)(rowbase + rt * 16 + col16) * D + quad * 32);

    float sums[4][4];
    #pragma unroll
    for (int rt = 0; rt < 4; ++rt)
        #pragma unroll
        for (int r = 0; r < 4; ++r) sums[rt][r] = 0.f;

    // 25 tiles/stream, padded to 28; clamped tails get g=-inf -> exp2=0.
    int8v bA, bB, bC, bD;
    float gA, gB, gC, gD;
    LOADT8(bA, gA, s);
    LOADT8(bB, gB, s + 128);
    LOADT8(bC, gC, s + 256);
    LOADT8(bD, gD, s + 384);
    #pragma unroll 1
    for (int j = 0; j < 24; j += 4) {
        COMP8(bA, gA); LOADT8(bA, gA, s + (j + 4) * 128);
        COMP8(bB, gB); LOADT8(bB, gB, s + (j + 5) * 128);
        COMP8(bC, gC); LOADT8(bC, gC, s + (j + 6) * 128);
        COMP8(bD, gD); LOADT8(bD, gD, s + (j + 7) * 128);
    }
    COMP8(bA, gA); COMP8(bB, gB); COMP8(bC, gC); COMP8(bD, gD);

    #pragma unroll
    for (int off = 1; off < 16; off <<= 1)
        #pragma unroll
        for (int rt = 0; rt < 4; ++rt)
            #pragma unroll
            for (int r = 0; r < 4; ++r)
                sums[rt][r] += __shfl_xor(sums[rt][r], off, 64);

    if (col16 == 0) {
        #pragma unroll
        for (int rt = 0; rt < 4; ++rt)
            #pragma unroll
            for (int r = 0; r < 4; ++r) {
                const int row = rowbase + rt * 16 + quad * 4 + r;
                part_s[row * NSTREAM + s] = sums[rt][r];
            }
    }
}

// ---------------- Kernel C: finalize (fp32 W_gen, L3-warm), one atomic/block ----------------
__global__ __launch_bounds__(256) void k_final(
    const float* __restrict__ z, const float* __restrict__ W_gen,
    const float* __restrict__ b_gen, const int* __restrict__ ctxw,
    const float* __restrict__ part_s, const float* __restrict__ kl,
    float* __restrict__ out)
{
    const int t = threadIdx.x;
    const int wv = t >> 6;
    const int lane = t & 63;
    __shared__ float red[4];

    float wsum = 0.f;
    #pragma unroll
    for (int rr = 0; rr < 2; ++rr) {
        const int b = blockIdx.x * 8 + wv * 2 + rr;

        int idxs[C];
        #pragma unroll
        for (int c = 0; c < C; ++c) idxs[c] = ctxw[b * C + c];
        float2 wv2[C];
        #pragma unroll
        for (int c = 0; c < C; ++c)
            wv2[c] = *(const float2*)(W_gen + (size_t)idxs[c] * D + lane * 2);
        float sum_bg = 0.f;
        #pragma unroll
        for (int c = 0; c < C; ++c) sum_bg += b_gen[idxs[c]];

        float sv = part_s[b * NSTREAM + lane] + part_s[b * NSTREAM + 64 + lane];
        const float z0 = z[b * D + lane * 2];
        const float z1 = z[b * D + lane * 2 + 1];

        float acc = 0.f;
        #pragma unroll
        for (int c = 0; c < C; ++c) {
            acc = fmaf(z0, wv2[c].x, acc);
            acc = fmaf(z1, wv2[c].y, acc);
        }
        #pragma unroll
        for (int off = 32; off > 0; off >>= 1) {
            sv  += __shfl_xor(sv, off, 64);
            acc += __shfl_xor(acc, off, 64);
        }
        if (lane == 0) {
            const float lse = logf(sv);
            const float recon = acc + sum_bg - C * lse;
            wsum += kl[b] - recon;
        }
    }
    if (lane == 0) red[wv] = wsum;
    __syncthreads();
    if (t == 0) atomicAdd(out, (red[0] + red[1] + red[2] + red[3]) * (1.f / B));
}

extern "C" void kernel_launch(void* const* d_in, const int* in_sizes, int n_in,
                              void* d_out, int out_size, void* d_ws, size_t ws_size,
                              hipStream_t stream) {
    const int* x_batch = (const int*)d_in[0];
    const int* ctxw    = (const int*)d_in[1];
    const float* eps   = (const float*)d_in[2];
    const float* inf_emb = (const float*)d_in[3];
    const float* W_aff = (const float*)d_in[4];
    const float* b_aff = (const float*)d_in[5];
    const float* W_mu  = (const float*)d_in[6];
    const float* b_mu  = (const float*)d_in[7];
    const float* W_sig = (const float*)d_in[8];
    const float* b_sig = (const float*)d_in[9];
    const float* gen_sig = (const float*)d_in[10];
    const float* W_gen = (const float*)d_in[11];
    const float* b_gen = (const float*)d_in[12];
    float* out = (float*)d_out;

    char* ws = (char*)d_ws;
    float* z      = (float*)ws;   ws += (size_t)B * D * 4;
    float* part_s = (float*)ws;   ws += (size_t)B * NSTREAM * 4;
    float* kl     = (float*)ws;   ws += (size_t)B * 4;
    float* bg2    = (float*)ws;   ws += (size_t)NVPAD * 4;
    unsigned char* z8 = (unsigned char*)ws;  ws += (size_t)B * D;
    unsigned char* w8 = (unsigned char*)ws;  ws += (size_t)NVPAD * D;
    short* waff_bf = (short*)ws;  ws += (size_t)128 * 256 * 2;
    short* wmu_bf  = (short*)ws;  ws += (size_t)128 * 128 * 2;
    short* wsig_bf = (short*)ws;  ws += (size_t)128 * 128 * 2;

    const int conv_items = NG4 + 16384 + NVPAD / 4;
    hipLaunchKernelGGL(k_convert, dim3((conv_items + 255) / 256), dim3(256), 0, stream,
                       W_gen, W_aff, W_mu, W_sig, b_gen,
                       w8, waff_bf, wmu_bf, wsig_bf, bg2, out);
    hipLaunchKernelGGL(k_infer, dim3(B / 16), dim3(512), 0, stream,
                       x_batch, ctxw, eps, inf_emb, waff_bf, b_aff, wmu_bf, b_mu,
                       wsig_bf, b_sig, gen_sig, z, z8, kl);
    hipLaunchKernelGGL(k_lse_mfma, dim3(8 * NSTREAM), dim3(256), 0, stream,
                       z8, w8, bg2, part_s);
    hipLaunchKernelGGL(k_final, dim3(B / 8), dim3(256), 0, stream,
                       z, W_gen, b_gen, ctxw, part_s, kl, out);
}

// Round 9
// 183.459 us; speedup vs baseline: 1.3763x; 1.0376x over previous
//
#include <hip/hip_runtime.h>
#include <float.h>
#include <math.h>

#define NV 50257
#define D 128
#define B 2048
#define C 10

#define NVPAD 50272                 // 3142 * 16
#define NTILES (NVPAD / 16)         // 3142 col-tiles of 16
#define NSTREAM 128                 // vocab streams
#define NG4 (NVPAD * D / 4)         // int (=4 fp8) count of packed W_gen
#define LOG2E 1.44269504088896f
#define SC1 0x7F7F7F7F              // e8m0 scale = 1.0 in every byte

typedef __attribute__((ext_vector_type(8))) short short8;
typedef __attribute__((ext_vector_type(8))) int int8v;
typedef __attribute__((ext_vector_type(4))) float float4v;

__device__ __forceinline__ float softplus_f(float x) {
    return fmaxf(x, 0.f) + log1pf(expf(-fabsf(x)));
}

__device__ __forceinline__ short f2bf(float f) {
    unsigned u = __float_as_uint(f);
    unsigned r = (u + 0x7FFFu + ((u >> 16) & 1u)) >> 16;   // RNE
    return (short)r;
}

// ---------------- Kernel P: small-weight bf16 + bg2 table + out zero (tiny) ----------------
__global__ __launch_bounds__(256) void k_pre(
    const float* __restrict__ waff, const float* __restrict__ wmu,
    const float* __restrict__ wsig, const float* __restrict__ b_gen,
    short* __restrict__ waff_o, short* __restrict__ wmu_o,
    short* __restrict__ wsig_o, float* __restrict__ bg2, float* __restrict__ out)
{
    const int j = blockIdx.x * 256 + threadIdx.x;
    if (j == 0) out[0] = 0.f;
    if (j < 16384) {
        const float4* src; short4* dst; int jj;
        if (j < 8192)       { src = (const float4*)waff; dst = (short4*)waff_o; jj = j; }
        else if (j < 12288) { src = (const float4*)wmu;  dst = (short4*)wmu_o;  jj = j - 8192; }
        else                { src = (const float4*)wsig; dst = (short4*)wsig_o; jj = j - 12288; }
        const float4 g = src[jj];
        short4 o;
        o.x = f2bf(g.x); o.y = f2bf(g.y); o.z = f2bf(g.z); o.w = f2bf(g.w);
        dst[jj] = o;
    } else {
        const int jj = j - 16384;
        if (jj < NVPAD / 4) {
            const int e0 = jj * 4;
            float4 o;
            o.x = (e0 + 0 < NV) ? b_gen[e0 + 0] * LOG2E : -INFINITY;
            o.y = (e0 + 1 < NV) ? b_gen[e0 + 1] * LOG2E : -INFINITY;
            o.z = (e0 + 2 < NV) ? b_gen[e0 + 2] * LOG2E : -INFINITY;
            o.w = (e0 + 3 < NV) ? b_gen[e0 + 3] * LOG2E : -INFINITY;
            ((float4*)bg2)[jj] = o;
        }
    }
}

// ---------------- Kernel M: fused [inference net (blocks 0..127)] + [W_gen->fp8 conv] ------
// Infer blocks: 640 thr = 10 waves, one context per wave (no tail), U split across
// waves via LDS (computed once, not 8x). Conv blocks (bid>=128): stream-pack fp8.
#define CONVB 629                   // ceil(NG4 / (640*4))
__global__ __launch_bounds__(640) void k_main(
    const int* __restrict__ x_batch, const int* __restrict__ ctxw,
    const float* __restrict__ eps, const float* __restrict__ inf_emb,
    const short* __restrict__ waff_bf, const float* __restrict__ b_aff,
    const short* __restrict__ wmu_bf, const float* __restrict__ b_mu,
    const short* __restrict__ wsig_bf, const float* __restrict__ b_sig,
    const float* __restrict__ gen_sig_emb, const float* __restrict__ wg,
    unsigned char* __restrict__ w8,
    float* __restrict__ z_out, unsigned char* __restrict__ z8_out,
    float* __restrict__ kl_out)
{
    const int bid = blockIdx.x;
    const int t = threadIdx.x;

    __shared__ float us[16][132];        // U tile, C-layout
    __shared__ float hsp[10][16][132];   // per-wave relu partials
    __shared__ float kl_s[8][16];

    if (bid >= 128) {
        // ---- conversion path: 4 strided int-writes (16 fp8) per thread ----
        const int base = (bid - 128) * (640 * 4) + t;
        #pragma unroll
        for (int k = 0; k < 4; ++k) {
            const int i4 = base + k * 640;
            if (i4 < NG4) {
                const int e0 = i4 * 4;
                int pk = 0;
                if (e0 < NV * D) {
                    const float4 g = ((const float4*)wg)[i4];
                    pk = __builtin_amdgcn_cvt_pk_fp8_f32(g.x, g.y, 0, false);
                    pk = __builtin_amdgcn_cvt_pk_fp8_f32(g.z, g.w, pk, true);
                }
                ((int*)w8)[i4] = pk;
            }
        }
        return;
    }

    // ---- inference path ----
    const int b0 = bid * 16;
    const int wv = t >> 6;           // 0..9
    const int lane = t & 63;
    const int col16 = lane & 15;
    const int quad = lane >> 4;
    const int brow = b0 + col16;

    // context gather: exactly one ctx per wave (issued first; loads stay in flight)
    const int widx = ctxw[brow * C + wv];
    short8 cx[4];
    #pragma unroll
    for (int ks = 0; ks < 4; ++ks) {
        const float* p = inf_emb + (size_t)widx * D + ks * 32 + quad * 8;
        const float4 g0 = *(const float4*)p;
        const float4 g1 = *(const float4*)(p + 4);
        short8 v;
        v[0] = f2bf(g0.x); v[1] = f2bf(g0.y); v[2] = f2bf(g0.z); v[3] = f2bf(g0.w);
        v[4] = f2bf(g1.x); v[5] = f2bf(g1.y); v[6] = f2bf(g1.z); v[7] = f2bf(g1.w);
        cx[ks] = v;
    }

    // U phase: wave wv (<8) computes dt-tile wv once, shares via LDS
    if (wv < 8) {
        const int cidx = x_batch[brow];
        short8 ce[4];
        #pragma unroll
        for (int ks = 0; ks < 4; ++ks) {
            const float* p = inf_emb + (size_t)cidx * D + ks * 32 + quad * 8;
            const float4 g0 = *(const float4*)p;
            const float4 g1 = *(const float4*)(p + 4);
            short8 v;
            v[0] = f2bf(g0.x); v[1] = f2bf(g0.y); v[2] = f2bf(g0.z); v[3] = f2bf(g0.w);
            v[4] = f2bf(g1.x); v[5] = f2bf(g1.y); v[6] = f2bf(g1.z); v[7] = f2bf(g1.w);
            ce[ks] = v;
        }
        float4v acc = {0.f, 0.f, 0.f, 0.f};
        #pragma unroll
        for (int ks = 0; ks < 4; ++ks) {
            const short8 bw = *(const short8*)(waff_bf + (wv * 16 + col16) * 256 + ks * 32 + quad * 8);
            acc = __builtin_amdgcn_mfma_f32_16x16x32_bf16(ce[ks], bw, acc, 0, 0, 0);
        }
        #pragma unroll
        for (int r = 0; r < 4; ++r)
            us[quad * 4 + r][wv * 16 + col16] = acc[r];
    }
    __syncthreads();

    // all 10 waves: read U, run own ctx GEMM, relu, write partial slab
    float ba[8];
    #pragma unroll
    for (int dt = 0; dt < 8; ++dt) ba[dt] = b_aff[dt * 16 + col16];

    #pragma unroll
    for (int dt = 0; dt < 8; ++dt) {
        float4v a = {0.f, 0.f, 0.f, 0.f};
        #pragma unroll
        for (int ks = 0; ks < 4; ++ks) {
            const short8 bw = *(const short8*)(waff_bf + (dt * 16 + col16) * 256 + 128 + ks * 32 + quad * 8);
            a = __builtin_amdgcn_mfma_f32_16x16x32_bf16(cx[ks], bw, a, 0, 0, 0);
        }
        #pragma unroll
        for (int r = 0; r < 4; ++r) {
            const float u = us[quad * 4 + r][dt * 16 + col16];
            hsp[wv][quad * 4 + r][dt * 16 + col16] = fmaxf(u + a[r] + ba[dt], 0.f);
        }
    }
    __syncthreads();

    // waves 0..7: sum 10 slabs -> A-frags, GEMM2 (nt=wv), epilogue
    if (wv < 8) {
        short8 ha[4];
        #pragma unroll
        for (int ks = 0; ks < 4; ++ks) {
            const int off = ks * 32 + quad * 8;
            float4 s0 = {0.f, 0.f, 0.f, 0.f}, s1 = {0.f, 0.f, 0.f, 0.f};
            #pragma unroll
            for (int w = 0; w < 10; ++w) {
                const float4 a0 = *(const float4*)&hsp[w][col16][off];
                const float4 a1 = *(const float4*)&hsp[w][col16][off + 4];
                s0.x += a0.x; s0.y += a0.y; s0.z += a0.z; s0.w += a0.w;
                s1.x += a1.x; s1.y += a1.y; s1.z += a1.z; s1.w += a1.w;
            }
            short8 v;
            v[0] = f2bf(s0.x); v[1] = f2bf(s0.y); v[2] = f2bf(s0.z); v[3] = f2bf(s0.w);
            v[4] = f2bf(s1.x); v[5] = f2bf(s1.y); v[6] = f2bf(s1.z); v[7] = f2bf(s1.w);
            ha[ks] = v;
        }

        int xb2[4];
        #pragma unroll
        for (int r = 0; r < 4; ++r) xb2[r] = x_batch[b0 + quad * 4 + r];

        const int nt = wv;
        float4v mu4 = {0.f, 0.f, 0.f, 0.f};
        float4v sg4 = {0.f, 0.f, 0.f, 0.f};
        #pragma unroll
        for (int ks = 0; ks < 4; ++ks) {
            const short8 bm = *(const short8*)(wmu_bf + (nt * 16 + col16) * 128 + ks * 32 + quad * 8);
            const short8 bs = *(const short8*)(wsig_bf + (nt * 16 + col16) * 128 + ks * 32 + quad * 8);
            mu4 = __builtin_amdgcn_mfma_f32_16x16x32_bf16(ha[ks], bm, mu4, 0, 0, 0);
            sg4 = __builtin_amdgcn_mfma_f32_16x16x32_bf16(ha[ks], bs, sg4, 0, 0, 0);
        }
        const int d = nt * 16 + col16;
        const float bmu = b_mu[d];
        const float bsg = b_sig[d];
        float klp[4];
        #pragma unroll
        for (int r = 0; r < 4; ++r) {
            const int b = b0 + quad * 4 + r;
            const float mu = mu4[r] + bmu;
            const float sg = sg4[r] + bsg;
            const float isig = softplus_f(sg);
            const float e = eps[b * D + d];
            const float zz = fmaf(e, isig, mu);
            z_out[b * D + d] = zz;
            const int pk = __builtin_amdgcn_cvt_pk_fp8_f32(zz * LOG2E, 0.f, 0, false);
            z8_out[b * D + d] = (unsigned char)(pk & 0xFF);
            const float gs = softplus_f(gen_sig_emb[(size_t)xb2[r] * D + d]);
            const float diff = mu - gs;
            klp[r] = logf(gs / isig) + (isig * isig + diff * diff) / (2.f * gs * gs) - 0.5f;
        }
        #pragma unroll
        for (int off = 1; off < 16; off <<= 1)
            #pragma unroll
            for (int r = 0; r < 4; ++r)
                klp[r] += __shfl_xor(klp[r], off, 64);
        if (col16 == 0) {
            #pragma unroll
            for (int r = 0; r < 4; ++r)
                kl_s[wv][quad * 4 + r] = klp[r];
        }
    }
    __syncthreads();
    if (t < 16) {
        float s = 0.f;
        #pragma unroll
        for (int w = 0; w < 8; ++w) s += kl_s[w][t];
        kl_out[b0 + t] = s;
    }
}

// ---------------- Kernel B: MX-fp8 K=128 MFMA sum-exp, 4-tile register pipeline --------
#define LOADT8(bf, g, T) { \
    const int v_ = (T) < NTILES; \
    const int tt_ = v_ ? (T) : 0; \
    bf = *(const int8v*)(w8 + (size_t)(tt_ * 16 + col16) * D + quad * 32); \
    g = v_ ? bg2t[tt_ * 16 + col16] : -INFINITY; }

#define COMP8(bf, g) { \
    _Pragma("unroll") \
    for (int rt = 0; rt < 4; ++rt) { \
        float4v c = {g, g, g, g}; \
        c = __builtin_amdgcn_mfma_scale_f32_16x16x128_f8f6f4( \
                afrag[rt], bf, c, 0, 0, 0, SC1, 0, SC1); \
        _Pragma("unroll") \
        for (int r = 0; r < 4; ++r) \
            sums[rt][r] += __builtin_amdgcn_exp2f(c[r]); \
    } }

__global__ __launch_bounds__(256) void k_lse_mfma(
    const unsigned char* __restrict__ z8, const unsigned char* __restrict__ w8,
    const float* __restrict__ bg2t, float* __restrict__ part_s)
{
    const int bid = blockIdx.x;
    const int s = bid & 127;                        // stream; XCD = s%8
    const int x = bid >> 7;                         // row block (256 rows)
    const int t = threadIdx.x;
    const int wv = t >> 6;
    const int lane = t & 63;
    const int col16 = lane & 15;
    const int quad = lane >> 4;
    const int rowbase = x * 256 + wv * 64;

    int8v afrag[4];
    #pragma unroll
    for (int rt = 0; rt < 4; ++rt)
        afrag[rt] = *(const int8v*)(z8 + (size_t)(rowbase + rt * 16 + col16) * D + quad * 32);

    float sums[4][4];
    #pragma unroll
    for (int rt = 0; rt < 4; ++rt)
        #pragma unroll
        for (int r = 0; r < 4; ++r) sums[rt][r] = 0.f;

    int8v bA, bB, bC, bD;
    float gA, gB, gC, gD;
    LOADT8(bA, gA, s);
    LOADT8(bB, gB, s + 128);
    LOADT8(bC, gC, s + 256);
    LOADT8(bD, gD, s + 384);
    #pragma unroll 1
    for (int j = 0; j < 24; j += 4) {
        COMP8(bA, gA); LOADT8(bA, gA, s + (j + 4) * 128);
        COMP8(bB, gB); LOADT8(bB, gB, s + (j + 5) * 128);
        COMP8(bC, gC); LOADT8(bC, gC, s + (j + 6) * 128);
        COMP8(bD, gD); LOADT8(bD, gD, s + (j + 7) * 128);
    }
    COMP8(bA, gA); COMP8(bB, gB); COMP8(bC, gC); COMP8(bD, gD);

    #pragma unroll
    for (int off = 1; off < 16; off <<= 1)
        #pragma unroll
        for (int rt = 0; rt < 4; ++rt)
            #pragma unroll
            for (int r = 0; r < 4; ++r)
                sums[rt][r] += __shfl_xor(sums[rt][r], off, 64);

    if (col16 == 0) {
        #pragma unroll
        for (int rt = 0; rt < 4; ++rt)
            #pragma unroll
            for (int r = 0; r < 4; ++r) {
                const int row = rowbase + rt * 16 + quad * 4 + r;
                part_s[row * NSTREAM + s] = sums[rt][r];
            }
    }
}

// ---------------- Kernel C: finalize (fp32 W_gen, L3-warm), one atomic/block ----------------
__global__ __launch_bounds__(256) void k_final(
    const float* __restrict__ z, const float* __restrict__ W_gen,
    const float* __restrict__ b_gen, const int* __restrict__ ctxw,
    const float* __restrict__ part_s, const float* __restrict__ kl,
    float* __restrict__ out)
{
    const int t = threadIdx.x;
    const int wv = t >> 6;
    const int lane = t & 63;
    __shared__ float red[4];

    float wsum = 0.f;
    #pragma unroll
    for (int rr = 0; rr < 2; ++rr) {
        const int b = blockIdx.x * 8 + wv * 2 + rr;

        int idxs[C];
        #pragma unroll
        for (int c = 0; c < C; ++c) idxs[c] = ctxw[b * C + c];
        float2 wv2[C];
        #pragma unroll
        for (int c = 0; c < C; ++c)
            wv2[c] = *(const float2*)(W_gen + (size_t)idxs[c] * D + lane * 2);
        float sum_bg = 0.f;
        #pragma unroll
        for (int c = 0; c < C; ++c) sum_bg += b_gen[idxs[c]];

        float sv = part_s[b * NSTREAM + lane] + part_s[b * NSTREAM + 64 + lane];
        const float z0 = z[b * D + lane * 2];
        const float z1 = z[b * D + lane * 2 + 1];

        float acc = 0.f;
        #pragma unroll
        for (int c = 0; c < C; ++c) {
            acc = fmaf(z0, wv2[c].x, acc);
            acc = fmaf(z1, wv2[c].y, acc);
        }
        #pragma unroll
        for (int off = 32; off > 0; off >>= 1) {
            sv  += __shfl_xor(sv, off, 64);
            acc += __shfl_xor(acc, off, 64);
        }
        if (lane == 0) {
            const float lse = logf(sv);
            const float recon = acc + sum_bg - C * lse;
            wsum += kl[b] - recon;
        }
    }
    if (lane == 0) red[wv] = wsum;
    __syncthreads();
    if (t == 0) atomicAdd(out, (red[0] + red[1] + red[2] + red[3]) * (1.f / B));
}

extern "C" void kernel_launch(void* const* d_in, const int* in_sizes, int n_in,
                              void* d_out, int out_size, void* d_ws, size_t ws_size,
                              hipStream_t stream) {
    const int* x_batch = (const int*)d_in[0];
    const int* ctxw    = (const int*)d_in[1];
    const float* eps   = (const float*)d_in[2];
    const float* inf_emb = (const float*)d_in[3];
    const float* W_aff = (const float*)d_in[4];
    const float* b_aff = (const float*)d_in[5];
    const float* W_mu  = (const float*)d_in[6];
    const float* b_mu  = (const float*)d_in[7];
    const float* W_sig = (const float*)d_in[8];
    const float* b_sig = (const float*)d_in[9];
    const float* gen_sig = (const float*)d_in[10];
    const float* W_gen = (const float*)d_in[11];
    const float* b_gen = (const float*)d_in[12];
    float* out = (float*)d_out;

    char* ws = (char*)d_ws;
    float* z      = (float*)ws;   ws += (size_t)B * D * 4;
    float* part_s = (float*)ws;   ws += (size_t)B * NSTREAM * 4;
    float* kl     = (float*)ws;   ws += (size_t)B * 4;
    float* bg2    = (float*)ws;   ws += (size_t)NVPAD * 4;
    unsigned char* z8 = (unsigned char*)ws;  ws += (size_t)B * D;
    unsigned char* w8 = (unsigned char*)ws;  ws += (size_t)NVPAD * D;
    short* waff_bf = (short*)ws;  ws += (size_t)128 * 256 * 2;
    short* wmu_bf  = (short*)ws;  ws += (size_t)128 * 128 * 2;
    short* wsig_bf = (short*)ws;  ws += (size_t)128 * 128 * 2;

    const int pre_items = 16384 + NVPAD / 4;
    hipLaunchKernelGGL(k_pre, dim3((pre_items + 255) / 256), dim3(256), 0, stream,
                       W_aff, W_mu, W_sig, b_gen,
                       waff_bf, wmu_bf, wsig_bf, bg2, out);
    hipLaunchKernelGGL(k_main, dim3(128 + CONVB), dim3(640), 0, stream,
                       x_batch, ctxw, eps, inf_emb, waff_bf, b_aff, wmu_bf, b_mu,
                       wsig_bf, b_sig, gen_sig, W_gen, w8, z, z8, kl);
    hipLaunchKernelGGL(k_lse_mfma, dim3(8 * NSTREAM), dim3(256), 0, stream,
                       z8, w8, bg2, part_s);
    hipLaunchKernelGGL(k_final, dim3(B / 8), dim3(256), 0, stream,
                       z, W_gen, b_gen, ctxw, part_s, kl, out);
}

// Round 10
// 177.206 us; speedup vs baseline: 1.4249x; 1.0353x over previous
//
#include <hip/hip_runtime.h>
#include <float.h>
#include <math.h>

#define NV 50257
#define D 128
#define B 2048
#define C 10

#define NVPAD 50272                 // 3142 * 16
#define NTILES (NVPAD / 16)         // 3142 col-tiles of 16
#define NSTREAM 128                 // vocab streams
#define NG4 (NVPAD * D / 4)         // int (=4 fp8) count of packed W_gen
#define LOG2E 1.44269504088896f
#define SC1 0x7F7F7F7F              // e8m0 scale = 1.0 in every byte

typedef __attribute__((ext_vector_type(8))) short short8;
typedef __attribute__((ext_vector_type(8))) int int8v;
typedef __attribute__((ext_vector_type(4))) float float4v;
typedef __attribute__((ext_vector_type(2))) float float2v;

__device__ __forceinline__ float softplus_f(float x) {
    return fmaxf(x, 0.f) + log1pf(expf(-fabsf(x)));
}

__device__ __forceinline__ short f2bf(float f) {
    unsigned u = __float_as_uint(f);
    unsigned r = (u + 0x7FFFu + ((u >> 16) & 1u)) >> 16;   // RNE
    return (short)r;
}

// ---------------- Kernel P: small-weight bf16 + bg2 table + out zero (tiny) ----------------
__global__ __launch_bounds__(256) void k_pre(
    const float* __restrict__ waff, const float* __restrict__ wmu,
    const float* __restrict__ wsig, const float* __restrict__ b_gen,
    short* __restrict__ waff_o, short* __restrict__ wmu_o,
    short* __restrict__ wsig_o, float* __restrict__ bg2, float* __restrict__ out)
{
    const int j = blockIdx.x * 256 + threadIdx.x;
    if (j == 0) out[0] = 0.f;
    if (j < 16384) {
        const float4* src; short4* dst; int jj;
        if (j < 8192)       { src = (const float4*)waff; dst = (short4*)waff_o; jj = j; }
        else if (j < 12288) { src = (const float4*)wmu;  dst = (short4*)wmu_o;  jj = j - 8192; }
        else                { src = (const float4*)wsig; dst = (short4*)wsig_o; jj = j - 12288; }
        const float4 g = src[jj];
        short4 o;
        o.x = f2bf(g.x); o.y = f2bf(g.y); o.z = f2bf(g.z); o.w = f2bf(g.w);
        dst[jj] = o;
    } else {
        const int jj = j - 16384;
        if (jj < NVPAD / 4) {
            const int e0 = jj * 4;
            float4 o;
            o.x = (e0 + 0 < NV) ? b_gen[e0 + 0] * LOG2E : -INFINITY;
            o.y = (e0 + 1 < NV) ? b_gen[e0 + 1] * LOG2E : -INFINITY;
            o.z = (e0 + 2 < NV) ? b_gen[e0 + 2] * LOG2E : -INFINITY;
            o.w = (e0 + 3 < NV) ? b_gen[e0 + 3] * LOG2E : -INFINITY;
            ((float4*)bg2)[jj] = o;
        }
    }
}

// ---------------- Kernel M: fused [inference net (blocks 0..127)] + [W_gen->fp8 conv] ------
// Infer blocks: 640 thr = 10 waves, one ctx per wave. LDS cut to ~50 KB: hsp has 5
// slabs; waves 5..9 accumulate into slabs 0..4 after a barrier (2-3 blocks/CU now).
#define CONVB 629                   // ceil(NG4 / (640*4))
__global__ __launch_bounds__(640) void k_main(
    const int* __restrict__ x_batch, const int* __restrict__ ctxw,
    const float* __restrict__ eps, const float* __restrict__ inf_emb,
    const short* __restrict__ waff_bf, const float* __restrict__ b_aff,
    const short* __restrict__ wmu_bf, const float* __restrict__ b_mu,
    const short* __restrict__ wsig_bf, const float* __restrict__ b_sig,
    const float* __restrict__ gen_sig_emb, const float* __restrict__ wg,
    unsigned char* __restrict__ w8,
    float* __restrict__ z_out, unsigned char* __restrict__ z8_out,
    float* __restrict__ kl_out)
{
    const int bid = blockIdx.x;
    const int t = threadIdx.x;

    __shared__ float us[16][132];        // U tile, C-layout (8.4 KB)
    __shared__ float hsp[5][16][132];    // relu partials, 5 slabs (42.2 KB)
    __shared__ float kl_s[8][16];

    if (bid >= 128) {
        // ---- conversion path: 4 strided int-writes (16 fp8) per thread ----
        const int base = (bid - 128) * (640 * 4) + t;
        #pragma unroll
        for (int k = 0; k < 4; ++k) {
            const int i4 = base + k * 640;
            if (i4 < NG4) {
                const int e0 = i4 * 4;
                int pk = 0;
                if (e0 < NV * D) {
                    const float4 g = ((const float4*)wg)[i4];
                    pk = __builtin_amdgcn_cvt_pk_fp8_f32(g.x, g.y, 0, false);
                    pk = __builtin_amdgcn_cvt_pk_fp8_f32(g.z, g.w, pk, true);
                }
                ((int*)w8)[i4] = pk;
            }
        }
        return;
    }

    // ---- inference path ----
    const int b0 = bid * 16;
    const int wv = t >> 6;           // 0..9
    const int lane = t & 63;
    const int col16 = lane & 15;
    const int quad = lane >> 4;
    const int brow = b0 + col16;

    // context gather: exactly one ctx per wave
    const int widx = ctxw[brow * C + wv];
    short8 cx[4];
    #pragma unroll
    for (int ks = 0; ks < 4; ++ks) {
        const float* p = inf_emb + (size_t)widx * D + ks * 32 + quad * 8;
        const float4 g0 = *(const float4*)p;
        const float4 g1 = *(const float4*)(p + 4);
        short8 v;
        v[0] = f2bf(g0.x); v[1] = f2bf(g0.y); v[2] = f2bf(g0.z); v[3] = f2bf(g0.w);
        v[4] = f2bf(g1.x); v[5] = f2bf(g1.y); v[6] = f2bf(g1.z); v[7] = f2bf(g1.w);
        cx[ks] = v;
    }

    // U phase: wave wv (<8) computes dt-tile wv once, shares via LDS
    if (wv < 8) {
        const int cidx = x_batch[brow];
        short8 ce[4];
        #pragma unroll
        for (int ks = 0; ks < 4; ++ks) {
            const float* p = inf_emb + (size_t)cidx * D + ks * 32 + quad * 8;
            const float4 g0 = *(const float4*)p;
            const float4 g1 = *(const float4*)(p + 4);
            short8 v;
            v[0] = f2bf(g0.x); v[1] = f2bf(g0.y); v[2] = f2bf(g0.z); v[3] = f2bf(g0.w);
            v[4] = f2bf(g1.x); v[5] = f2bf(g1.y); v[6] = f2bf(g1.z); v[7] = f2bf(g1.w);
            ce[ks] = v;
        }
        float4v acc = {0.f, 0.f, 0.f, 0.f};
        #pragma unroll
        for (int ks = 0; ks < 4; ++ks) {
            const short8 bw = *(const short8*)(waff_bf + (wv * 16 + col16) * 256 + ks * 32 + quad * 8);
            acc = __builtin_amdgcn_mfma_f32_16x16x32_bf16(ce[ks], bw, acc, 0, 0, 0);
        }
        #pragma unroll
        for (int r = 0; r < 4; ++r)
            us[quad * 4 + r][wv * 16 + col16] = acc[r];
    }
    __syncthreads();

    // all 10 waves: own ctx GEMM + relu into registers
    float ba[8];
    #pragma unroll
    for (int dt = 0; dt < 8; ++dt) ba[dt] = b_aff[dt * 16 + col16];

    float4v H[8];
    #pragma unroll
    for (int dt = 0; dt < 8; ++dt) {
        float4v a = {0.f, 0.f, 0.f, 0.f};
        #pragma unroll
        for (int ks = 0; ks < 4; ++ks) {
            const short8 bw = *(const short8*)(waff_bf + (dt * 16 + col16) * 256 + 128 + ks * 32 + quad * 8);
            a = __builtin_amdgcn_mfma_f32_16x16x32_bf16(cx[ks], bw, a, 0, 0, 0);
        }
        #pragma unroll
        for (int r = 0; r < 4; ++r) {
            const float u = us[quad * 4 + r][dt * 16 + col16];
            H[dt][r] = fmaxf(u + a[r] + ba[dt], 0.f);
        }
    }

    // two-phase slab commit: waves 0-4 write, waves 5-9 accumulate
    if (wv < 5) {
        #pragma unroll
        for (int dt = 0; dt < 8; ++dt)
            #pragma unroll
            for (int r = 0; r < 4; ++r)
                hsp[wv][quad * 4 + r][dt * 16 + col16] = H[dt][r];
    }
    __syncthreads();
    if (wv >= 5) {
        #pragma unroll
        for (int dt = 0; dt < 8; ++dt)
            #pragma unroll
            for (int r = 0; r < 4; ++r)
                hsp[wv - 5][quad * 4 + r][dt * 16 + col16] += H[dt][r];
    }
    __syncthreads();

    // waves 0..7: sum 5 slabs -> A-frags, GEMM2 (nt=wv), epilogue
    if (wv < 8) {
        short8 ha[4];
        #pragma unroll
        for (int ks = 0; ks < 4; ++ks) {
            const int off = ks * 32 + quad * 8;
            float4 s0 = {0.f, 0.f, 0.f, 0.f}, s1 = {0.f, 0.f, 0.f, 0.f};
            #pragma unroll
            for (int w = 0; w < 5; ++w) {
                const float4 a0 = *(const float4*)&hsp[w][col16][off];
                const float4 a1 = *(const float4*)&hsp[w][col16][off + 4];
                s0.x += a0.x; s0.y += a0.y; s0.z += a0.z; s0.w += a0.w;
                s1.x += a1.x; s1.y += a1.y; s1.z += a1.z; s1.w += a1.w;
            }
            short8 v;
            v[0] = f2bf(s0.x); v[1] = f2bf(s0.y); v[2] = f2bf(s0.z); v[3] = f2bf(s0.w);
            v[4] = f2bf(s1.x); v[5] = f2bf(s1.y); v[6] = f2bf(s1.z); v[7] = f2bf(s1.w);
            ha[ks] = v;
        }

        int xb2[4];
        #pragma unroll
        for (int r = 0; r < 4; ++r) xb2[r] = x_batch[b0 + quad * 4 + r];

        const int nt = wv;
        float4v mu4 = {0.f, 0.f, 0.f, 0.f};
        float4v sg4 = {0.f, 0.f, 0.f, 0.f};
        #pragma unroll
        for (int ks = 0; ks < 4; ++ks) {
            const short8 bm = *(const short8*)(wmu_bf + (nt * 16 + col16) * 128 + ks * 32 + quad * 8);
            const short8 bs = *(const short8*)(wsig_bf + (nt * 16 + col16) * 128 + ks * 32 + quad * 8);
            mu4 = __builtin_amdgcn_mfma_f32_16x16x32_bf16(ha[ks], bm, mu4, 0, 0, 0);
            sg4 = __builtin_amdgcn_mfma_f32_16x16x32_bf16(ha[ks], bs, sg4, 0, 0, 0);
        }
        const int d = nt * 16 + col16;
        const float bmu = b_mu[d];
        const float bsg = b_sig[d];
        float klp[4];
        #pragma unroll
        for (int r = 0; r < 4; ++r) {
            const int b = b0 + quad * 4 + r;
            const float mu = mu4[r] + bmu;
            const float sg = sg4[r] + bsg;
            const float isig = softplus_f(sg);
            const float e = eps[b * D + d];
            const float zz = fmaf(e, isig, mu);
            z_out[b * D + d] = zz;
            const int pk = __builtin_amdgcn_cvt_pk_fp8_f32(zz * LOG2E, 0.f, 0, false);
            z8_out[b * D + d] = (unsigned char)(pk & 0xFF);
            const float gs = softplus_f(gen_sig_emb[(size_t)xb2[r] * D + d]);
            const float diff = mu - gs;
            klp[r] = logf(gs / isig) + (isig * isig + diff * diff) / (2.f * gs * gs) - 0.5f;
        }
        #pragma unroll
        for (int off = 1; off < 16; off <<= 1)
            #pragma unroll
            for (int r = 0; r < 4; ++r)
                klp[r] += __shfl_xor(klp[r], off, 64);
        if (col16 == 0) {
            #pragma unroll
            for (int r = 0; r < 4; ++r)
                kl_s[wv][quad * 4 + r] = klp[r];
        }
    }
    __syncthreads();
    if (t < 16) {
        float s = 0.f;
        #pragma unroll
        for (int w = 0; w < 8; ++w) s += kl_s[w][t];
        kl_out[b0 + t] = s;
    }
}

// ---------------- Kernel B: MX-fp8 K=128 MFMA sum-exp, exact 25-tile pipeline ----------
#define LOADT8(bf, g, T) { \
    const int v_ = (T) < NTILES; \
    const int tt_ = v_ ? (T) : 0; \
    bf = *(const int8v*)(w8 + (size_t)(tt_ * 16 + col16) * D + quad * 32); \
    g = v_ ? bg2t[tt_ * 16 + col16] : -INFINITY; }

#define COMP8(bf, g) { \
    _Pragma("unroll") \
    for (int rt = 0; rt < 4; ++rt) { \
        float4v c = {g, g, g, g}; \
        c = __builtin_amdgcn_mfma_scale_f32_16x16x128_f8f6f4( \
                afrag[rt], bf, c, 0, 0, 0, SC1, 0, SC1); \
        _Pragma("unroll") \
        for (int r = 0; r < 4; ++r) \
            sums[rt][r] += __builtin_amdgcn_exp2f(c[r]); \
    } }

__global__ __launch_bounds__(256) void k_lse_mfma(
    const unsigned char* __restrict__ z8, const unsigned char* __restrict__ w8,
    const float* __restrict__ bg2t, float* __restrict__ part_s)
{
    const int bid = blockIdx.x;
    const int s = bid & 127;                        // stream; XCD = s%8
    const int x = bid >> 7;                         // row block (256 rows)
    const int t = threadIdx.x;
    const int wv = t >> 6;
    const int lane = t & 63;
    const int col16 = lane & 15;
    const int quad = lane >> 4;
    const int rowbase = x * 256 + wv * 64;

    int8v afrag[4];
    #pragma unroll
    for (int rt = 0; rt < 4; ++rt)
        afrag[rt] = *(const int8v*)(z8 + (size_t)(rowbase + rt * 16 + col16) * D + quad * 32);

    float sums[4][4];
    #pragma unroll
    for (int rt = 0; rt < 4; ++rt)
        #pragma unroll
        for (int r = 0; r < 4; ++r) sums[rt][r] = 0.f;

    // exactly 25 tiles (streams s>=70 have 24; only the last is clamped -> -inf).
    int8v bA, bB, bC, bD;
    float gA, gB, gC, gD;
    LOADT8(bA, gA, s);
    LOADT8(bB, gB, s + 128);
    LOADT8(bC, gC, s + 256);
    LOADT8(bD, gD, s + 384);
    #pragma unroll 1
    for (int j = 0; j < 20; j += 4) {               // computes tiles j..j+3
        COMP8(bA, gA); LOADT8(bA, gA, s + (j + 4) * 128);
        COMP8(bB, gB); LOADT8(bB, gB, s + (j + 5) * 128);
        COMP8(bC, gC); LOADT8(bC, gC, s + (j + 6) * 128);
        COMP8(bD, gD); LOADT8(bD, gD, s + (j + 7) * 128);
    }
    COMP8(bA, gA);                                  // tile 20
    COMP8(bB, gB); COMP8(bC, gC); COMP8(bD, gD);    // tiles 21..23
    LOADT8(bA, gA, s + 24 * 128);
    COMP8(bA, gA);                                  // tile 24 (clamped for s>=70)

    #pragma unroll
    for (int off = 1; off < 16; off <<= 1)
        #pragma unroll
        for (int rt = 0; rt < 4; ++rt)
            #pragma unroll
            for (int r = 0; r < 4; ++r)
                sums[rt][r] += __shfl_xor(sums[rt][r], off, 64);

    if (col16 == 0) {
        #pragma unroll
        for (int rt = 0; rt < 4; ++rt)
            #pragma unroll
            for (int r = 0; r < 4; ++r) {
                const int row = rowbase + rt * 16 + quad * 4 + r;
                part_s[row * NSTREAM + s] = sums[rt][r];
            }
    }
}

// ---------------- Kernel C: finalize (fp8 ctx gather, L2-hot), one atomic/block ----------------
__global__ __launch_bounds__(256) void k_final(
    const float* __restrict__ z, const unsigned char* __restrict__ w8,
    const float* __restrict__ b_gen, const int* __restrict__ ctxw,
    const float* __restrict__ part_s, const float* __restrict__ kl,
    float* __restrict__ out)
{
    const int t = threadIdx.x;
    const int wv = t >> 6;
    const int lane = t & 63;
    __shared__ float red[4];

    float wsum = 0.f;
    #pragma unroll
    for (int rr = 0; rr < 2; ++rr) {
        const int b = blockIdx.x * 8 + wv * 2 + rr;

        int idxs[C];
        #pragma unroll
        for (int c = 0; c < C; ++c) idxs[c] = ctxw[b * C + c];
        unsigned short uw[C];
        #pragma unroll
        for (int c = 0; c < C; ++c)
            uw[c] = *(const unsigned short*)(w8 + (size_t)idxs[c] * D + lane * 2);
        float sum_bg = 0.f;
        #pragma unroll
        for (int c = 0; c < C; ++c) sum_bg += b_gen[idxs[c]];

        float sv = part_s[b * NSTREAM + lane] + part_s[b * NSTREAM + 64 + lane];
        const float z0 = z[b * D + lane * 2];
        const float z1 = z[b * D + lane * 2 + 1];

        float acc = 0.f;
        #pragma unroll
        for (int c = 0; c < C; ++c) {
            const float2v wf = __builtin_amdgcn_cvt_pk_f32_fp8((int)uw[c], false);
            acc = fmaf(z0, wf[0], acc);
            acc = fmaf(z1, wf[1], acc);
        }
        #pragma unroll
        for (int off = 32; off > 0; off >>= 1) {
            sv  += __shfl_xor(sv, off, 64);
            acc += __shfl_xor(acc, off, 64);
        }
        if (lane == 0) {
            const float lse = logf(sv);
            const float recon = acc + sum_bg - C * lse;
            wsum += kl[b] - recon;
        }
    }
    if (lane == 0) red[wv] = wsum;
    __syncthreads();
    if (t == 0) atomicAdd(out, (red[0] + red[1] + red[2] + red[3]) * (1.f / B));
}

extern "C" void kernel_launch(void* const* d_in, const int* in_sizes, int n_in,
                              void* d_out, int out_size, void* d_ws, size_t ws_size,
                              hipStream_t stream) {
    const int* x_batch = (const int*)d_in[0];
    const int* ctxw    = (const int*)d_in[1];
    const float* eps   = (const float*)d_in[2];
    const float* inf_emb = (const float*)d_in[3];
    const float* W_aff = (const float*)d_in[4];
    const float* b_aff = (const float*)d_in[5];
    const float* W_mu  = (const float*)d_in[6];
    const float* b_mu  = (const float*)d_in[7];
    const float* W_sig = (const float*)d_in[8];
    const float* b_sig = (const float*)d_in[9];
    const float* gen_sig = (const float*)d_in[10];
    const float* W_gen = (const float*)d_in[11];
    const float* b_gen = (const float*)d_in[12];
    float* out = (float*)d_out;

    char* ws = (char*)d_ws;
    float* z      = (float*)ws;   ws += (size_t)B * D * 4;
    float* part_s = (float*)ws;   ws += (size_t)B * NSTREAM * 4;
    float* kl     = (float*)ws;   ws += (size_t)B * 4;
    float* bg2    = (float*)ws;   ws += (size_t)NVPAD * 4;
    unsigned char* z8 = (unsigned char*)ws;  ws += (size_t)B * D;
    unsigned char* w8 = (unsigned char*)ws;  ws += (size_t)NVPAD * D;
    short* waff_bf = (short*)ws;  ws += (size_t)128 * 256 * 2;
    short* wmu_bf  = (short*)ws;  ws += (size_t)128 * 128 * 2;
    short* wsig_bf = (short*)ws;  ws += (size_t)128 * 128 * 2;

    const int pre_items = 16384 + NVPAD / 4;
    hipLaunchKernelGGL(k_pre, dim3((pre_items + 255) / 256), dim3(256), 0, stream,
                       W_aff, W_mu, W_sig, b_gen,
                       waff_bf, wmu_bf, wsig_bf, bg2, out);
    hipLaunchKernelGGL(k_main, dim3(128 + CONVB), dim3(640), 0, stream,
                       x_batch, ctxw, eps, inf_emb, waff_bf, b_aff, wmu_bf, b_mu,
                       wsig_bf, b_sig, gen_sig, W_gen, w8, z, z8, kl);
    hipLaunchKernelGGL(k_lse_mfma, dim3(8 * NSTREAM), dim3(256), 0, stream,
                       z8, w8, bg2, part_s);
    hipLaunchKernelGGL(k_final, dim3(B / 8), dim3(256), 0, stream,
                       z, w8, b_gen, ctxw, part_s, kl, out);
}